// Round 7
// baseline (1217.231 us; speedup 1.0000x reference)
//
#include <hip/hip_runtime.h>
#include <hip/hip_bf16.h>
#include <stdint.h>

// ---------------------------------------------------------------------------
// MambaEncoder forward. Round 7: no cooperative launch (round-4 proven 3-kernel
// scan), keep conv-fused dbc GEMM + reduce-fused dt GEMM, bf16 delta/y.
// ---------------------------------------------------------------------------

#define SEQ     4096
#define DMODEL  1024
#define DINNER  2048
#define NSTATE  16
#define DTRANK  64
#define NLAYERS 4
#define LC      64    // scan chunk length
#define NC      64    // number of chunks (SEQ/LC)
#define SPLITK  4
#define SPDBC   (SEQ * 96)

typedef __attribute__((ext_vector_type(8))) short short8v;   // 8 bf16 (4 VGPRs)
typedef __attribute__((ext_vector_type(4))) float f32x4;
typedef __hip_bfloat16 bf16;

__device__ __forceinline__ float b2f(unsigned short x) {
    unsigned int u = ((unsigned int)x) << 16;
    return __builtin_bit_cast(float, u);
}
__device__ __forceinline__ unsigned short f2b(float x) {
    return __builtin_bit_cast(unsigned short, __float2bfloat16(x));
}
__device__ __forceinline__ unsigned int pk2(float a, float b) {
    return (unsigned int)f2b(a) | ((unsigned int)f2b(b) << 16);
}

// ------------------------------------------------------------ async g->LDS 16B
__device__ __forceinline__ void gld16(const void* gsrc, void* ldst) {
    __builtin_amdgcn_global_load_lds(
        (const __attribute__((address_space(1))) void*)gsrc,
        (__attribute__((address_space(3))) void*)ldst, 16, 0, 0);
}

// ---------------------------------------------------------------- block sum
__device__ __forceinline__ float block_sum(float v, float* red, int nwaves) {
    #pragma unroll
    for (int o = 32; o > 0; o >>= 1) v += __shfl_down(v, o, 64);
    int lane = threadIdx.x & 63, w = threadIdx.x >> 6;
    __syncthreads();
    if (lane == 0) red[w] = v;
    __syncthreads();
    float s = red[0];
    for (int i = 1; i < nwaves; i++) s += red[i];
    return s;
}

// ------------------------------------------------- layernorm row, width=1024
template<bool BF16OUT>
__global__ void ln1024_kernel(const float* __restrict__ X, const float* __restrict__ X2,
                              const float* __restrict__ g, const float* __restrict__ bta,
                              void* __restrict__ out, float eps) {
    __shared__ float red[4];
    int s = blockIdx.x, tid = threadIdx.x;
    size_t base = (size_t)s * 1024;
    int c = tid * 4;
    float4 v = *(const float4*)(X + base + c);
    if (X2) {
        float4 w = *(const float4*)(X2 + base + c);
        v.x += w.x; v.y += w.y; v.z += w.z; v.w += w.w;
    }
    float mu = block_sum(v.x + v.y + v.z + v.w, red, 4) * (1.f / 1024);
    float sq = (v.x - mu) * (v.x - mu) + (v.y - mu) * (v.y - mu)
             + (v.z - mu) * (v.z - mu) + (v.w - mu) * (v.w - mu);
    float var = block_sum(sq, red, 4) * (1.f / 1024);
    float rstd = rsqrtf(var + eps);
    float4 gg = *(const float4*)(g + c);
    float4 bb = *(const float4*)(bta + c);
    float o0 = (v.x - mu) * rstd * gg.x + bb.x;
    float o1 = (v.y - mu) * rstd * gg.y + bb.y;
    float o2 = (v.z - mu) * rstd * gg.z + bb.z;
    float o3 = (v.w - mu) * rstd * gg.w + bb.w;
    if (BF16OUT) {
        uint2 o; o.x = pk2(o0, o1); o.y = pk2(o2, o3);
        *(uint2*)((unsigned short*)out + base + c) = o;
    } else {
        float4 o = {o0, o1, o2, o3};
        *(float4*)((float*)out + base + c) = o;
    }
}

// --------------------------------------------------- outnorm + silu(z) gate
__global__ void outnorm_silu_kernel(const unsigned short* __restrict__ y,
                                    const unsigned short* __restrict__ xz,
                                    const float* __restrict__ g, const float* __restrict__ bta,
                                    unsigned short* __restrict__ p, float eps) {
    __shared__ float red[4];
    int s = blockIdx.x, tid = threadIdx.x;
    int c = tid * 8;
    size_t base = (size_t)s * DINNER;
    uint4 yv = *(const uint4*)(y + base + c);
    float v[8] = {b2f((unsigned short)(yv.x & 0xffff)), b2f((unsigned short)(yv.x >> 16)),
                  b2f((unsigned short)(yv.y & 0xffff)), b2f((unsigned short)(yv.y >> 16)),
                  b2f((unsigned short)(yv.z & 0xffff)), b2f((unsigned short)(yv.z >> 16)),
                  b2f((unsigned short)(yv.w & 0xffff)), b2f((unsigned short)(yv.w >> 16))};
    float sum = 0.f;
    #pragma unroll
    for (int i = 0; i < 8; i++) sum += v[i];
    float mu = block_sum(sum, red, 4) * (1.f / DINNER);
    float sq = 0.f;
    #pragma unroll
    for (int i = 0; i < 8; i++) { float dd = v[i] - mu; sq += dd * dd; }
    float var = block_sum(sq, red, 4) * (1.f / DINNER);
    float rstd = rsqrtf(var + eps);
    uint4 zv = *(const uint4*)(xz + (size_t)s * 2 * DINNER + DINNER + c);
    float z[8] = {b2f((unsigned short)(zv.x & 0xffff)), b2f((unsigned short)(zv.x >> 16)),
                  b2f((unsigned short)(zv.y & 0xffff)), b2f((unsigned short)(zv.y >> 16)),
                  b2f((unsigned short)(zv.z & 0xffff)), b2f((unsigned short)(zv.z >> 16)),
                  b2f((unsigned short)(zv.w & 0xffff)), b2f((unsigned short)(zv.w >> 16))};
    float4 g0 = *(const float4*)(g + c),  g1 = *(const float4*)(g + c + 4);
    float4 b0 = *(const float4*)(bta + c), b1 = *(const float4*)(bta + c + 4);
    float gv[8] = {g0.x, g0.y, g0.z, g0.w, g1.x, g1.y, g1.z, g1.w};
    float bv[8] = {b0.x, b0.y, b0.z, b0.w, b1.x, b1.y, b1.z, b1.w};
    float o[8];
    #pragma unroll
    for (int i = 0; i < 8; i++) {
        float ln = (v[i] - mu) * rstd * gv[i] + bv[i];
        float sig = 1.f / (1.f + __expf(-z[i]));
        o[i] = ln * (z[i] * sig);
    }
    uint4 ov = {pk2(o[0], o[1]), pk2(o[2], o[3]), pk2(o[4], o[5]), pk2(o[6], o[7])};
    *(uint4*)(p + base + c) = ov;
}

// -------------------- fused fp32 -> bf16 cvt, ALL layers' weights, 1 launch
#define CN0 (2 * DINNER * DMODEL)   // 4194304 in_proj
#define CN1 (DMODEL * DINNER)       // 2097152 out_proj
#define CN2 (96 * DINNER)           //  196608 deltaBC
#define CN3 (DINNER * DTRANK)       //  131072 dt_proj
#define CPER ((size_t)(CN0 + CN1 + CN2 + CN3))
__global__ void cvt_all_kernel(const float* __restrict__ w0, const float* __restrict__ w1,
                               const float* __restrict__ w2, const float* __restrict__ w3,
                               bf16* __restrict__ o0, bf16* __restrict__ o1,
                               bf16* __restrict__ o2, bf16* __restrict__ o3) {
    size_t i = (size_t)(blockIdx.x * 256 + threadIdx.x) * 4;
    int L = (int)(i / CPER);
    size_t r = i - (size_t)L * CPER;
    const float* src; bf16* dst; size_t off;
    if (r < CN0)                   { src = w0 + (size_t)L * CN0; dst = o0 + (size_t)L * CN0; off = r; }
    else if (r < CN0 + CN1)        { src = w1 + (size_t)L * CN1; dst = o1 + (size_t)L * CN1; off = r - CN0; }
    else if (r < CN0 + CN1 + CN2)  { src = w2 + (size_t)L * CN2; dst = o2 + (size_t)L * CN2; off = r - CN0 - CN1; }
    else                           { src = w3 + (size_t)L * CN3; dst = o3 + (size_t)L * CN3; off = r - CN0 - CN1 - CN2; }
    float4 v = *(const float4*)(src + off);
    uint2 o; o.x = pk2(v.x, v.y); o.y = pk2(v.z, v.w);
    *(uint2*)((unsigned short*)dst + off) = o;
}

// ------------------- conv weight transpose: [L][2048][3] -> [L][3][2048] fp32
__global__ void conv_wt_kernel(const float* __restrict__ cw, float* __restrict__ cwT) {
    int gid = blockIdx.x * 256 + threadIdx.x;    // NLAYERS*2048
    int l = gid >> 11, c = gid & 2047;
    #pragma unroll
    for (int t = 0; t < 3; t++)
        cwT[((size_t)l * 3 + t) * 2048 + c] = cw[((size_t)l * 2048 + c) * 3 + t];
}

// --------------------------------------------------------- bf16 MFMA GEMM
// MODE 0: +bias, bf16 out (in_proj)   MODE 3: +bias, +res, f32 out (out_proj)
template<int MODE>
__global__ __launch_bounds__(256, 2)
void mfma_gemm(const bf16* __restrict__ A, int lda,
               const bf16* __restrict__ W, int ldw,
               const float* __restrict__ bias,
               float* __restrict__ C, int ldc,
               const float* __restrict__ res,
               bf16* __restrict__ Cbf,
               int M, int N, int K) {
    __shared__ __attribute__((aligned(16))) short sA[128][32];
    __shared__ __attribute__((aligned(16))) short sB[128][32];
    int tid = threadIdx.x;
    int lane = tid & 63, w = tid >> 6;
    int wm = w >> 1, wn = w & 1;
    int m0 = blockIdx.x * 128, n0 = blockIdx.y * 128;
    int r16 = lane & 15, quad = lane >> 4;
    int ldrow = (lane >> 2);
    int c8 = (lane & 3) * 8;

    f32x4 acc[4][4] = {};

    for (int k0 = 0; k0 < K; k0 += 32) {
        __syncthreads();
        #pragma unroll
        for (int j = 0; j < 2; j++) {
            int row = j * 64 + w * 16 + ldrow;
            gld16(A + (size_t)(m0 + row) * lda + k0 + c8,
                  (char*)&sA[0][0] + j * 4096 + w * 1024);
            gld16(W + (size_t)(n0 + row) * ldw + k0 + c8,
                  (char*)&sB[0][0] + j * 4096 + w * 1024);
        }
        __syncthreads();
        short8v aF[4], bF[4];
        #pragma unroll
        for (int mi = 0; mi < 4; mi++)
            aF[mi] = *(const short8v*)&sA[wm * 64 + mi * 16 + r16][quad * 8];
        #pragma unroll
        for (int ni = 0; ni < 4; ni++)
            bF[ni] = *(const short8v*)&sB[wn * 64 + ni * 16 + r16][quad * 8];
        #pragma unroll
        for (int mi = 0; mi < 4; mi++)
            #pragma unroll
            for (int ni = 0; ni < 4; ni++)
                acc[mi][ni] = __builtin_amdgcn_mfma_f32_16x16x32_bf16(
                    aF[mi], bF[ni], acc[mi][ni], 0, 0, 0);
    }

    #pragma unroll
    for (int mi = 0; mi < 4; mi++) {
        #pragma unroll
        for (int ni = 0; ni < 4; ni++) {
            f32x4 a = acc[mi][ni];
            int col = n0 + wn * 64 + ni * 16 + r16;
            int rbase = m0 + wm * 64 + mi * 16 + quad * 4;
            #pragma unroll
            for (int r = 0; r < 4; r++) {
                int row = rbase + r;
                float v = a[r] + bias[col];
                if (MODE == 3) v += res[(size_t)row * ldc + col];
                if (MODE == 0) Cbf[(size_t)row * ldc + col] = __float2bfloat16(v);
                else           C[(size_t)row * ldc + col] = v;
            }
        }
    }
}

// ---------------------- dbc GEMM with conv fused into A staging (split-K x4)
__global__ __launch_bounds__(256, 2)
void dbc_conv_gemm(const unsigned short* __restrict__ xz,
                   const float* __restrict__ cwT, const float* __restrict__ cb,
                   const bf16* __restrict__ W,
                   unsigned short* __restrict__ u16, float* __restrict__ Cp) {
    __shared__ __attribute__((aligned(16))) short sA[128][32];
    __shared__ __attribute__((aligned(16))) short sB[128][32];
    int tid = threadIdx.x;
    int lane = tid & 63, w = tid >> 6;
    int wm = w >> 1, wn = w & 1;
    int m0 = blockIdx.x * 128;
    int kz = blockIdx.z;
    int r16 = lane & 15, quad = lane >> 4;
    int ldrow = lane >> 2;
    int cg4 = (lane & 3) * 8;

    f32x4 acc[4][4] = {};

    for (int k0 = 0; k0 < 512; k0 += 32) {
        int cc = kz * 512 + k0 + cg4;            // channel base for this thread
        float4 w0a = *(const float4*)(cwT + 0 * 2048 + cc);
        float4 w0b = *(const float4*)(cwT + 0 * 2048 + cc + 4);
        float4 w1a = *(const float4*)(cwT + 1 * 2048 + cc);
        float4 w1b = *(const float4*)(cwT + 1 * 2048 + cc + 4);
        float4 w2a = *(const float4*)(cwT + 2 * 2048 + cc);
        float4 w2b = *(const float4*)(cwT + 2 * 2048 + cc + 4);
        float4 cba = *(const float4*)(cb + cc);
        float4 cbb = *(const float4*)(cb + cc + 4);
        float cw0[8] = {w0a.x,w0a.y,w0a.z,w0a.w,w0b.x,w0b.y,w0b.z,w0b.w};
        float cw1[8] = {w1a.x,w1a.y,w1a.z,w1a.w,w1b.x,w1b.y,w1b.z,w1b.w};
        float cw2[8] = {w2a.x,w2a.y,w2a.z,w2a.w,w2b.x,w2b.y,w2b.z,w2b.w};
        float cbv[8] = {cba.x,cba.y,cba.z,cba.w,cbb.x,cbb.y,cbb.z,cbb.w};
        __syncthreads();
        #pragma unroll
        for (int j = 0; j < 2; j++) {
            int row = j * 64 + w * 16 + ldrow;
            int s = m0 + row;
            const unsigned short* xr = xz + (size_t)s * (2 * DINNER) + cc;
            uint4 z4 = {0, 0, 0, 0};
            uint4 v0 = *(const uint4*)xr;
            uint4 vm = (s > 0)       ? *(const uint4*)(xr - 2 * DINNER) : z4;
            uint4 vp = (s < SEQ - 1) ? *(const uint4*)(xr + 2 * DINNER) : z4;
            unsigned int v0u[4] = {v0.x, v0.y, v0.z, v0.w};
            unsigned int vmu[4] = {vm.x, vm.y, vm.z, vm.w};
            unsigned int vpu[4] = {vp.x, vp.y, vp.z, vp.w};
            float uo[8];
            #pragma unroll
            for (int i = 0; i < 4; i++) {
                float x0l = b2f((unsigned short)(v0u[i] & 0xffff));
                float x0h = b2f((unsigned short)(v0u[i] >> 16));
                float xml = b2f((unsigned short)(vmu[i] & 0xffff));
                float xmh = b2f((unsigned short)(vmu[i] >> 16));
                float xpl = b2f((unsigned short)(vpu[i] & 0xffff));
                float xph = b2f((unsigned short)(vpu[i] >> 16));
                uo[2*i]   = cw0[2*i]   * xml + cw1[2*i]   * x0l + cw2[2*i]   * xpl + cbv[2*i];
                uo[2*i+1] = cw0[2*i+1] * xmh + cw1[2*i+1] * x0h + cw2[2*i+1] * xph + cbv[2*i+1];
            }
            uint4 up = {pk2(uo[0], uo[1]), pk2(uo[2], uo[3]),
                        pk2(uo[4], uo[5]), pk2(uo[6], uo[7])};
            *(uint4*)((char*)&sA[0][0] + row * 64 + (lane & 3) * 16) = up;
            *(uint4*)(u16 + (size_t)s * DINNER + cc) = up;
            int nr = row > 95 ? 95 : row;
            gld16(W + (size_t)nr * DINNER + kz * 512 + k0 + cg4,
                  (char*)&sB[0][0] + j * 4096 + w * 1024);
        }
        __syncthreads();
        short8v aF[4], bF[4];
        #pragma unroll
        for (int mi = 0; mi < 4; mi++)
            aF[mi] = *(const short8v*)&sA[wm * 64 + mi * 16 + r16][quad * 8];
        #pragma unroll
        for (int ni = 0; ni < 4; ni++)
            bF[ni] = *(const short8v*)&sB[wn * 64 + ni * 16 + r16][quad * 8];
        #pragma unroll
        for (int mi = 0; mi < 4; mi++)
            #pragma unroll
            for (int ni = 0; ni < 4; ni++)
                acc[mi][ni] = __builtin_amdgcn_mfma_f32_16x16x32_bf16(
                    aF[mi], bF[ni], acc[mi][ni], 0, 0, 0);
    }

    float* C = Cp + (size_t)kz * SPDBC;
    #pragma unroll
    for (int mi = 0; mi < 4; mi++) {
        #pragma unroll
        for (int ni = 0; ni < 4; ni++) {
            f32x4 a = acc[mi][ni];
            int col = wn * 64 + ni * 16 + r16;
            if (col >= 96) continue;
            int rbase = m0 + wm * 64 + mi * 16 + quad * 4;
            #pragma unroll
            for (int r = 0; r < 4; r++)
                C[(size_t)(rbase + r) * 96 + col] = a[r];
        }
    }
}

// -------------------- dt GEMM with split-K reduce fused into A staging
__global__ __launch_bounds__(256, 2)
void dt_gemm(const float* __restrict__ dbcp, const bf16* __restrict__ W,
             const float* __restrict__ bias, unsigned short* __restrict__ dlt) {
    __shared__ __attribute__((aligned(16))) short sA[128][32];
    __shared__ __attribute__((aligned(16))) short sB[128][32];
    int tid = threadIdx.x;
    int lane = tid & 63, w = tid >> 6;
    int wm = w >> 1, wn = w & 1;
    int m0 = blockIdx.x * 128, n0 = blockIdx.y * 128;
    int r16 = lane & 15, quad = lane >> 4;
    int ldrow = lane >> 2;
    int c8 = (lane & 3) * 8;

    f32x4 acc[4][4] = {};

    #pragma unroll
    for (int k0 = 0; k0 < 64; k0 += 32) {
        __syncthreads();
        #pragma unroll
        for (int j = 0; j < 2; j++) {
            int row = j * 64 + w * 16 + ldrow;
            int s = m0 + row;
            size_t o = (size_t)s * 96 + k0 + c8;
            float4 aa = {0,0,0,0}, ab = {0,0,0,0};
            #pragma unroll
            for (int p = 0; p < SPLITK; p++) {
                float4 t0 = *(const float4*)(dbcp + o + (size_t)p * SPDBC);
                float4 t1 = *(const float4*)(dbcp + o + (size_t)p * SPDBC + 4);
                aa.x += t0.x; aa.y += t0.y; aa.z += t0.z; aa.w += t0.w;
                ab.x += t1.x; ab.y += t1.y; ab.z += t1.z; ab.w += t1.w;
            }
            uint4 up = {pk2(aa.x, aa.y), pk2(aa.z, aa.w), pk2(ab.x, ab.y), pk2(ab.z, ab.w)};
            *(uint4*)((char*)&sA[0][0] + row * 64 + (lane & 3) * 16) = up;
            gld16(W + (size_t)(n0 + row) * DTRANK + k0 + c8,
                  (char*)&sB[0][0] + j * 4096 + w * 1024);
        }
        __syncthreads();
        short8v aF[4], bF[4];
        #pragma unroll
        for (int mi = 0; mi < 4; mi++)
            aF[mi] = *(const short8v*)&sA[wm * 64 + mi * 16 + r16][quad * 8];
        #pragma unroll
        for (int ni = 0; ni < 4; ni++)
            bF[ni] = *(const short8v*)&sB[wn * 64 + ni * 16 + r16][quad * 8];
        #pragma unroll
        for (int mi = 0; mi < 4; mi++)
            #pragma unroll
            for (int ni = 0; ni < 4; ni++)
                acc[mi][ni] = __builtin_amdgcn_mfma_f32_16x16x32_bf16(
                    aF[mi], bF[ni], acc[mi][ni], 0, 0, 0);
    }

    #pragma unroll
    for (int mi = 0; mi < 4; mi++) {
        #pragma unroll
        for (int ni = 0; ni < 4; ni++) {
            f32x4 a = acc[mi][ni];
            int col = n0 + wn * 64 + ni * 16 + r16;
            int rbase = m0 + wm * 64 + mi * 16 + quad * 4;
            #pragma unroll
            for (int r = 0; r < 4; r++) {
                float v = a[r] + bias[col];
                v = (v > 20.f) ? v : log1pf(__expf(v));
                dlt[(size_t)(rbase + r) * DINNER + col] = f2b(v);
            }
        }
    }
}

// --------------------------------------------------- exp-chain detection
__device__ __forceinline__ bool a_is_neg_integers(const float* a) {
    bool fast = true;
    #pragma unroll
    for (int n = 0; n < NSTATE; n++)
        fast = fast && (__builtin_fabsf(a[n] + (float)(n + 1)) < 1e-3f * (n + 1));
    return fast;
}

// ------------------------------------------------------- chunked scan pass 1
__global__ void scan1_kernel(const unsigned short* __restrict__ dl16,
                             const unsigned short* __restrict__ uu16,
                             const float* __restrict__ dbcp, const float* __restrict__ A_log,
                             float* __restrict__ h_end, float* __restrict__ dsum) {
    __shared__ __attribute__((aligned(16))) float sB[LC][NSTATE];
    int k = blockIdx.x, d = blockIdx.y * 256 + threadIdx.x;
    int s0 = k * LC, tid = threadIdx.x;
    #pragma unroll
    for (int i = 0; i < 4; i++) {
        int idx = tid + i * 256;                 // LC*16 = 1024
        int r = idx >> 4, n = idx & 15;
        size_t o = (size_t)(s0 + r) * 96 + DTRANK + n;
        sB[r][n] = dbcp[o] + dbcp[o + SPDBC] + dbcp[o + 2 * SPDBC] + dbcp[o + 3 * SPDBC];
    }
    float a[NSTATE];
    #pragma unroll
    for (int n = 0; n < NSTATE; n++) a[n] = -__expf(A_log[(size_t)d * NSTATE + n]);
    bool fast = a_is_neg_integers(a);
    __syncthreads();
    float h[NSTATE] = {}; float ds = 0.f;
    if (fast) {
        #pragma unroll 2
        for (int r = 0; r < LC; r++) {
            float dl = b2f(dl16[(size_t)(s0 + r) * DINNER + d]);
            float du = dl * b2f(uu16[(size_t)(s0 + r) * DINNER + d]);
            ds += dl;
            float g = __expf(-dl);
            float Bv[NSTATE];
            #pragma unroll
            for (int q = 0; q < 4; q++) *(float4*)&Bv[q * 4] = *(const float4*)&sB[r][q * 4];
            float fac = 1.f;
            #pragma unroll
            for (int n = 0; n < NSTATE; n++) { fac *= g; h[n] = fac * h[n] + du * Bv[n]; }
        }
    } else {
        #pragma unroll 2
        for (int r = 0; r < LC; r++) {
            float dl = b2f(dl16[(size_t)(s0 + r) * DINNER + d]);
            float du = dl * b2f(uu16[(size_t)(s0 + r) * DINNER + d]);
            ds += dl;
            float Bv[NSTATE];
            #pragma unroll
            for (int q = 0; q < 4; q++) *(float4*)&Bv[q * 4] = *(const float4*)&sB[r][q * 4];
            #pragma unroll
            for (int n = 0; n < NSTATE; n++) h[n] = __expf(dl * a[n]) * h[n] + du * Bv[n];
        }
    }
    #pragma unroll
    for (int n = 0; n < NSTATE; n++)
        h_end[((size_t)k * NSTATE + n) * DINNER + d] = h[n];
    dsum[(size_t)k * DINNER + d] = ds;
}

// ------------------------------------------------------- chunked scan pass 2
__global__ void scan2_kernel(const float* __restrict__ A_log, const float* __restrict__ dsum,
                             const float* __restrict__ h_end, float* __restrict__ hinit) {
    int id = blockIdx.x * 256 + threadIdx.x;     // DINNER*NSTATE
    int d = id & (DINNER - 1), n = id >> 11;
    float a = -__expf(A_log[(size_t)d * NSTATE + n]);
    float h = 0.f;
    for (int k = 0; k < NC; k++) {
        size_t off = ((size_t)k * NSTATE + n) * DINNER + d;
        hinit[off] = h;
        h = __expf(a * dsum[(size_t)k * DINNER + d]) * h + h_end[off];
    }
}

// ------------------------------------------------------- chunked scan pass 3
__global__ void scan3_kernel(unsigned short* __restrict__ dl_y16,
                             const unsigned short* __restrict__ uu16,
                             const float* __restrict__ dbcp, const float* __restrict__ A_log,
                             const float* __restrict__ Dp, const float* __restrict__ hinit) {
    __shared__ __attribute__((aligned(16))) float sB[LC][NSTATE];
    __shared__ __attribute__((aligned(16))) float sC[LC][NSTATE];
    int k = blockIdx.x, d = blockIdx.y * 256 + threadIdx.x;
    int s0 = k * LC, tid = threadIdx.x;
    #pragma unroll
    for (int i = 0; i < 8; i++) {
        int idx = tid + i * 256;                 // LC*32 = 2048
        int r = idx >> 5, c = idx & 31;
        size_t o = (size_t)(s0 + r) * 96 + DTRANK + c;
        float v = dbcp[o] + dbcp[o + SPDBC] + dbcp[o + 2 * SPDBC] + dbcp[o + 3 * SPDBC];
        if (c < 16) sB[r][c] = v; else sC[r][c - 16] = v;
    }
    float a[NSTATE];
    #pragma unroll
    for (int n = 0; n < NSTATE; n++) a[n] = -__expf(A_log[(size_t)d * NSTATE + n]);
    bool fast = a_is_neg_integers(a);
    float h[NSTATE];
    #pragma unroll
    for (int n = 0; n < NSTATE; n++)
        h[n] = hinit[((size_t)k * NSTATE + n) * DINNER + d];
    float dpv = Dp[d];
    __syncthreads();
    if (fast) {
        #pragma unroll 2
        for (int r = 0; r < LC; r++) {
            float dl = b2f(dl_y16[(size_t)(s0 + r) * DINNER + d]);
            float uu = b2f(uu16[(size_t)(s0 + r) * DINNER + d]);
            float du = dl * uu;
            float g = __expf(-dl);
            float Bv[NSTATE], Cv[NSTATE];
            #pragma unroll
            for (int q = 0; q < 4; q++) {
                *(float4*)&Bv[q * 4] = *(const float4*)&sB[r][q * 4];
                *(float4*)&Cv[q * 4] = *(const float4*)&sC[r][q * 4];
            }
            float y = uu * dpv;
            float fac = 1.f;
            #pragma unroll
            for (int n = 0; n < NSTATE; n++) {
                fac *= g;
                h[n] = fac * h[n] + du * Bv[n];
                y += h[n] * Cv[n];
            }
            dl_y16[(size_t)(s0 + r) * DINNER + d] = f2b(y);
        }
    } else {
        #pragma unroll 2
        for (int r = 0; r < LC; r++) {
            float dl = b2f(dl_y16[(size_t)(s0 + r) * DINNER + d]);
            float uu = b2f(uu16[(size_t)(s0 + r) * DINNER + d]);
            float du = dl * uu;
            float Bv[NSTATE], Cv[NSTATE];
            #pragma unroll
            for (int q = 0; q < 4; q++) {
                *(float4*)&Bv[q * 4] = *(const float4*)&sB[r][q * 4];
                *(float4*)&Cv[q * 4] = *(const float4*)&sC[r][q * 4];
            }
            float y = uu * dpv;
            #pragma unroll
            for (int n = 0; n < NSTATE; n++) {
                h[n] = __expf(dl * a[n]) * h[n] + du * Bv[n];
                y += h[n] * Cv[n];
            }
            dl_y16[(size_t)(s0 + r) * DINNER + d] = f2b(y);
        }
    }
}

// ---------------------------------------------------------------------------
extern "C" void kernel_launch(void* const* d_in, const int* in_sizes, int n_in,
                              void* d_out, int out_size, void* d_ws, size_t ws_size,
                              hipStream_t stream) {
    const float* x         = (const float*)d_in[0];
    const float* pos       = (const float*)d_in[1];
    const float* ln_g      = (const float*)d_in[2];
    const float* ln_b      = (const float*)d_in[3];
    const float* innorm_g  = (const float*)d_in[4];
    const float* innorm_b  = (const float*)d_in[5];
    const float* in_proj_w = (const float*)d_in[6];
    const float* in_proj_b = (const float*)d_in[7];
    const float* conv_w    = (const float*)d_in[8];
    const float* conv_b    = (const float*)d_in[9];
    const float* deltaBC_w = (const float*)d_in[10];
    const float* dt_proj_w = (const float*)d_in[11];
    const float* dt_proj_b = (const float*)d_in[12];
    const float* A_log     = (const float*)d_in[13];
    const float* Dp        = (const float*)d_in[14];
    const float* outnorm_g = (const float*)d_in[15];
    const float* outnorm_b = (const float*)d_in[16];
    const float* out_proj_w= (const float*)d_in[17];
    const float* out_proj_b= (const float*)d_in[18];

    float* enc = (float*)d_out;
    char* ws = (char*)d_ws;
    const size_t MB = 1024 * 1024;
    bf16*  h_bf    = (bf16*) (ws + 0);           //  8 MB [S,d]  (aliased w/ p_bf)
    bf16*  p_bf    = (bf16*) (ws + 0);           // 16 MB [S,di]
    bf16*  xz_bf   = (bf16*) (ws + 16 * MB);     // 32 MB [S,2di]
    bf16*  dlt_bf  = (bf16*) (ws + 48 * MB);     // 16 MB delta -> y (in place, bf16)
    bf16*  u_bf    = (bf16*) (ws + 64 * MB);     // 16 MB [S,di]
    float* dbcp    = (float*)(ws + 80 * MB);     //  6 MB splitK partials [4,S,96]
    float* h_end   = (float*)(ws + 87 * MB);     //  8 MB [NC,n,di]
    float* hinit   = (float*)(ws + 95 * MB);     //  8 MB [NC,n,di]
    float* dsum    = (float*)(ws + 103 * MB);    // 0.5MB [NC,di]
    bf16*  w_in_a  = (bf16*) (ws + 104 * MB);    // 32 MB [L][2di,d]
    bf16*  w_out_a = (bf16*) (ws + 136 * MB);    // 16 MB [L][d,di]
    bf16*  w_dbc_a = (bf16*) (ws + 152 * MB);    // 1.5MB [L][96,di]
    bf16*  w_dt_a  = (bf16*) (ws + 154 * MB);    //  1 MB [L][di,r]
    float* cwT     = (float*)(ws + 155 * MB);    // 96KB [L][3][2048]

    // one-time weight prep
    cvt_all_kernel<<<(unsigned)((NLAYERS * CPER) / 1024), 256, 0, stream>>>(
        in_proj_w, out_proj_w, deltaBC_w, dt_proj_w, w_in_a, w_out_a, w_dbc_a, w_dt_a);
    conv_wt_kernel<<<(NLAYERS * 2048) / 256, 256, 0, stream>>>(conv_w, cwT);

    // enc = LN(x + pos_enc), eps=1e-6
    ln1024_kernel<false><<<SEQ, 256, 0, stream>>>(x, pos, ln_g, ln_b, enc, 1e-6f);

    for (int L = 0; L < NLAYERS; L++) {
        const float* Al  = A_log + (size_t)L * DINNER * NSTATE;
        const float* Dpl = Dp + (size_t)L * DINNER;
        bf16* w_in  = w_in_a  + (size_t)L * CN0;
        bf16* w_out = w_out_a + (size_t)L * CN1;
        bf16* w_dbc = w_dbc_a + (size_t)L * CN2;
        bf16* w_dt  = w_dt_a  + (size_t)L * CN3;

        ln1024_kernel<true><<<SEQ, 256, 0, stream>>>(enc, nullptr, innorm_g + L * DMODEL,
                                                     innorm_b + L * DMODEL, h_bf, 1e-5f);
        // xz = h @ in_proj_w^T + b  -> bf16   [4096 x 4096], K=1024
        mfma_gemm<0><<<dim3(32, 32), 256, 0, stream>>>(
            h_bf, DMODEL, w_in, DMODEL, in_proj_b + (size_t)L * 2 * DINNER,
            nullptr, 2 * DINNER, nullptr, xz_bf, SEQ, 2 * DINNER, DMODEL);
        // dbc partials = conv(x1) @ deltaBC_w^T  (conv fused; u written as side effect)
        dbc_conv_gemm<<<dim3(32, 1, SPLITK), 256, 0, stream>>>(
            (const unsigned short*)xz_bf, cwT + (size_t)L * 3 * 2048,
            conv_b + (size_t)L * DINNER, w_dbc,
            (unsigned short*)u_bf, dbcp);
        // delta = softplus(reduce(dbcp)[:, :64] @ dt_proj_w^T + b) -> bf16
        dt_gemm<<<dim3(32, 16), 256, 0, stream>>>(
            dbcp, w_dt, dt_proj_b + (size_t)L * DINNER, (unsigned short*)dlt_bf);
        // 3-pass chunked selective scan (non-cooperative); y overwrites dlt_bf
        scan1_kernel<<<dim3(NC, 8), 256, 0, stream>>>(
            (const unsigned short*)dlt_bf, (const unsigned short*)u_bf,
            dbcp, Al, h_end, dsum);
        scan2_kernel<<<(DINNER * NSTATE) / 256, 256, 0, stream>>>(Al, dsum, h_end, hinit);
        scan3_kernel<<<dim3(NC, 8), 256, 0, stream>>>(
            (unsigned short*)dlt_bf, (const unsigned short*)u_bf,
            dbcp, Al, Dpl, hinit);
        outnorm_silu_kernel<<<SEQ, 256, 0, stream>>>(
            (const unsigned short*)dlt_bf, (const unsigned short*)xz_bf,
            outnorm_g + L * DINNER, outnorm_b + L * DINNER,
            (unsigned short*)p_bf, 1e-5f);
        // enc = p @ out_proj_w^T + b + enc   [4096 x 1024], K=2048
        mfma_gemm<3><<<dim3(32, 8), 256, 0, stream>>>(
            p_bf, DINNER, w_out, DINNER, out_proj_b + L * DMODEL,
            enc, DMODEL, enc, nullptr, SEQ, DMODEL, DINNER);
    }
}